// Round 1
// baseline (222.254 us; speedup 1.0000x reference)
//
#include <hip/hip_runtime.h>

// Grouped rational (Pade) activation: y = P(x) / (1 + |x * q(x)|)
// B=4, L=4096, D=2048, G=8 -> dg=256 channels/group.
// Memory-bound elementwise: 268 MB total traffic, roofline ~43 us @ 6.3 TB/s.

#define N_GROUPS 8
#define D_CH 2048   // channels; group = (channel >> 8)

__global__ __launch_bounds__(256) void rational_act_kernel(
    const float* __restrict__ x,
    const float* __restrict__ num_v,   // (G, 6)
    const float* __restrict__ den_v,   // (G, 4)
    float* __restrict__ out,
    int n4)                            // total elements / 4
{
    const int i = blockIdx.x * blockDim.x + threadIdx.x;
    if (i >= n4) return;

    // Thread i handles flat channels [4i, 4i+4). Group boundaries are at
    // multiples of 256 channels, so a wave (64 lanes x float4 = 256 channels,
    // wave-aligned since blockDim=256) maps to EXACTLY one group:
    //   g = ((4i) % 2048) / 256 = (i >> 6) & 7   -- wave-uniform.
    // readfirstlane makes that provable to the compiler -> coeffs become
    // scalar loads (SGPRs), keeping the vector memory pipe for data only.
    const int g = __builtin_amdgcn_readfirstlane((i >> 6) & (N_GROUPS - 1));

    const float a0 = num_v[g * 6 + 0];
    const float a1 = num_v[g * 6 + 1];
    const float a2 = num_v[g * 6 + 2];
    const float a3 = num_v[g * 6 + 3];
    const float a4 = num_v[g * 6 + 4];
    const float a5 = num_v[g * 6 + 5];
    const float b0 = den_v[g * 4 + 0];
    const float b1 = den_v[g * 4 + 1];
    const float b2 = den_v[g * 4 + 2];
    const float b3 = den_v[g * 4 + 3];

    const float4 xv = reinterpret_cast<const float4*>(x)[i];
    float xs[4] = {xv.x, xv.y, xv.z, xv.w};
    float rs[4];

#pragma unroll
    for (int k = 0; k < 4; ++k) {
        const float xx = xs[k];
        // Horner numerator: a5*x^5 + ... + a0 (matches reference order)
        float num = fmaf(a5, xx, a4);
        num = fmaf(num, xx, a3);
        num = fmaf(num, xx, a2);
        num = fmaf(num, xx, a1);
        num = fmaf(num, xx, a0);
        // Horner q(x) = b3*x^3 + b2*x^2 + b1*x + b0
        float z = fmaf(b3, xx, b2);
        z = fmaf(z, xx, b1);
        z = fmaf(z, xx, b0);
        const float den = 1.0f + fabsf(xx * z);
        rs[k] = num / den;
    }

    float4 r;
    r.x = rs[0]; r.y = rs[1]; r.z = rs[2]; r.w = rs[3];
    reinterpret_cast<float4*>(out)[i] = r;
}

extern "C" void kernel_launch(void* const* d_in, const int* in_sizes, int n_in,
                              void* d_out, int out_size, void* d_ws, size_t ws_size,
                              hipStream_t stream) {
    const float* x    = (const float*)d_in[0];   // (B, L, D) fp32
    const float* nv   = (const float*)d_in[1];   // (G, 6) fp32
    const float* dv   = (const float*)d_in[2];   // (G, 4) fp32
    float* out        = (float*)d_out;           // (B, L, D) fp32

    const int n = out_size;          // 4*4096*2048 = 33,554,432
    const int n4 = n / 4;            // exact (power of two)
    const int threads = 256;
    const int blocks = (n4 + threads - 1) / threads;

    rational_act_kernel<<<blocks, threads, 0, stream>>>(x, nv, dv, out, n4);
}